// Round 2
// baseline (84.983 us; speedup 1.0000x reference)
//
#include <hip/hip_runtime.h>
#include <math.h>

#define NK      10000
#define LSEQ    512
#define KSMAX   11
#define ROWS_DW (514 * 4)                // staged f16x8 rows (pos=-1..512), dwords
#define RED_OFF ROWS_DW                  // stage-A region offset (dwords, even -> 8B aligned)
#define SM_DW   (ROWS_DW + 256 * 10)     // 2056 + 2560 = 4616 dwords = 18464 B -> 8 blocks/CU

typedef _Float16 half2v __attribute__((ext_vector_type(2)));

union H2U { half2v h; unsigned int u; };

__device__ __forceinline__ unsigned int rfl_u32(unsigned int v) {
    return (unsigned int)__builtin_amdgcn_readfirstlane((int)v);
}

template <int KS>
__device__ __forceinline__ void run_conv(const float4* __restrict__ rows,  // 16B f16x8 rows
                                         const unsigned int* whs,          // SGPR packed {w,w} f16
                                         half2v bb,
                                         int pad, int dl, int lk, int lane,
                                         half2v& m0, half2v& m1, half2v& m2, half2v& m3,
                                         half2v& c0, half2v& c1, half2v& c2, half2v& c3) {
    const half2v one2  = {(_Float16)1.0f, (_Float16)1.0f};
    const half2v zero2 = {(_Float16)0.0f, (_Float16)0.0f};
    const half2v big2  = {(_Float16)16384.0f, (_Float16)16384.0f};
    // per-tap offsets j*dl are wave-uniform -> scalar regs, hoisted out of the t-loop;
    // address chains per tap become independent (no serial pos += dl dependency)
    for (int t0 = 0; t0 < lk; t0 += 64) {     // this wave owns the whole k
        const int t = t0 + lane;
        half2v a0 = bb, a1 = bb, a2 = bb, a3 = bb;
        const int p0 = t - pad;
        #pragma unroll
        for (int j = 0; j < KS; ++j) {
            int pc = min(max(p0 + j * dl, -1), LSEQ);  // v_med3_i32; rows -1/512 are zeros
            float4 r = rows[pc + 1];                   // one ds_read_b128 per tap
            H2U uw; uw.u = whs[j];                     // SGPR operand of v_pk_fma_f16
            half2v wj = uw.h;
            a0 += wj * ((half2v*)&r)[0];               // v_pk_fma_f16
            a1 += wj * ((half2v*)&r)[1];
            a2 += wj * ((half2v*)&r)[2];
            a3 += wj * ((half2v*)&r)[3];
        }
        if (t < lk) {
            m0 = __builtin_elementwise_max(m0, a0);    // v_pk_max_f16
            m1 = __builtin_elementwise_max(m1, a1);
            m2 = __builtin_elementwise_max(m2, a2);
            m3 = __builtin_elementwise_max(m3, a3);
            // step(a) = clamp(a*16384, 0, 1): exact 0/1 for all normal f16
            c0 += __builtin_elementwise_min(__builtin_elementwise_max(a0 * big2, zero2), one2);
            c1 += __builtin_elementwise_min(__builtin_elementwise_max(a1 * big2, zero2), one2);
            c2 += __builtin_elementwise_min(__builtin_elementwise_max(a2 * big2, zero2), one2);
            c3 += __builtin_elementwise_min(__builtin_elementwise_max(a3 * big2, zero2), one2);
        }
    }
}

__global__ __launch_bounds__(256, 8) void rocket_kernel(
    const float* __restrict__ x, const float* __restrict__ W,
    const float* __restrict__ bias, const int* __restrict__ dil,
    const int* __restrict__ lo, float* __restrict__ out) {
    __shared__ __align__(16) float sm[SM_DW];
    const int tid  = threadIdx.x;
    const int wave = tid >> 6;
    const int lane = tid & 63;
    // k is wave-uniform: force it into an SGPR so ALL per-kernel params become s_loads
    const int k = __builtin_amdgcn_readfirstlane(blockIdx.x * 4 + wave);

    // ---- stage x -> LDS as f16, batch-major 16B rows; one row per thread ----
    #pragma unroll
    for (int i = 0; i < 2; ++i) {
        int p = tid + i * 256;
        half2v h0 = {(_Float16)x[0 * LSEQ + p], (_Float16)x[1 * LSEQ + p]};
        half2v h1 = {(_Float16)x[2 * LSEQ + p], (_Float16)x[3 * LSEQ + p]};
        half2v h2 = {(_Float16)x[4 * LSEQ + p], (_Float16)x[5 * LSEQ + p]};
        half2v h3 = {(_Float16)x[6 * LSEQ + p], (_Float16)x[7 * LSEQ + p]};
        float4 v;
        ((half2v*)&v)[0] = h0;
        ((half2v*)&v)[1] = h1;
        ((half2v*)&v)[2] = h2;
        ((half2v*)&v)[3] = h3;
        *(float4*)(sm + (size_t)(p + 1) * 4) = v;      // contiguous 16B rows
    }
    if (tid < 4)           sm[tid] = 0.0f;                   // row pos=-1
    else if (tid < 8)      sm[513 * 4 + (tid - 4)] = 0.0f;   // row pos=512

    // ---- per-kernel params, all scalar (k uniform): weights packed to SGPRs ----
    const float* Wk = W + (size_t)k * KSMAX;
    unsigned int whs[KSMAX];
    #pragma unroll
    for (int j = 0; j < KSMAX; ++j) {
        _Float16 wf = (_Float16)Wk[j];
        H2U u; u.h = (half2v){wf, wf};
        whs[j] = rfl_u32(u.u);
    }
    // ks classification on exact f32 scalars (padded taps are exactly 0)
    const float w7 = Wk[7], w8 = Wk[8], w9 = Wk[9], w10 = Wk[10];
    const bool z7 = (w7 == 0.0f) && (w8 == 0.0f) && (w9 == 0.0f) && (w10 == 0.0f);
    const bool z9 = (w9 == 0.0f) && (w10 == 0.0f);

    _Float16 bf = (_Float16)bias[k];
    H2U ub; ub.h = (half2v){bf, bf};
    ub.u = rfl_u32(ub.u);
    const half2v bb = ub.h;
    const int dl = dil[k];
    const int lk = lo[k];

    __syncthreads();   // the only block barrier: rows visible to all waves

    half2v mneg = {(_Float16)(-INFINITY), (_Float16)(-INFINITY)};
    half2v zz   = {(_Float16)0.0f, (_Float16)0.0f};
    half2v m0 = mneg, m1 = mneg, m2 = mneg, m3 = mneg;
    half2v c0 = zz,   c1 = zz,   c2 = zz,   c3 = zz;

    // pad from the reference identity: lo = 512 + 2*pad - dil*(ks-1)
    const float4* rows = (const float4*)sm;
    if (z7) {
        int pad = (lk - LSEQ + dl * 6) >> 1;
        run_conv<7 >(rows, whs, bb, pad, dl, lk, lane, m0, m1, m2, m3, c0, c1, c2, c3);
    } else if (z9) {
        int pad = (lk - LSEQ + dl * 8) >> 1;
        run_conv<9 >(rows, whs, bb, pad, dl, lk, lane, m0, m1, m2, m3, c0, c1, c2, c3);
    } else {
        int pad = (lk - LSEQ + dl * 10) >> 1;
        run_conv<11>(rows, whs, bb, pad, dl, lk, lane, m0, m1, m2, m3, c0, c1, c2, c3);
    }

    // ---- wave-internal epilogue (no barriers: same-wave DS ordering) ----
    {
        unsigned int* red = (unsigned int*)(sm + RED_OFF);   // disjoint from rows
        const int tb = tid * 10;                             // 40B stride, 8B aligned
        H2U u0, u1, u2, u3;
        uint2 p01, p23;
        u0.h = m0; u1.h = m1; u2.h = m2; u3.h = m3;
        p01.x = u0.u; p01.y = u1.u; p23.x = u2.u; p23.y = u3.u;
        *(uint2*)(red + tb + 0) = p01;
        *(uint2*)(red + tb + 2) = p23;
        u0.h = c0; u1.h = c1; u2.h = c2; u3.h = c3;
        p01.x = u0.u; p01.y = u1.u; p23.x = u2.u; p23.y = u3.u;
        *(uint2*)(red + tb + 4) = p01;
        *(uint2*)(red + tb + 6) = p23;

        // transpose-read own wave's region: lane (q,dv) reduces dword dv over tids {q+8i}
        const int q  = lane & 7;
        const int dv = lane >> 3;            // 0..3 = max half2, 4..7 = cnt half2
        const bool ismax = dv < 4;
        const int wbase = (tid & ~63) * 10;
        half2v r = ismax ? (half2v){(_Float16)(-INFINITY), (_Float16)(-INFINITY)}
                         : (half2v){(_Float16)0.0f, (_Float16)0.0f};
        #pragma unroll
        for (int i = 0; i < 8; ++i) {
            H2U t;
            t.u = red[wbase + (q + 8 * i) * 10 + dv];
            r = ismax ? __builtin_elementwise_max(r, t.h) : (r + t.h);
        }
        #pragma unroll
        for (int s = 1; s < 8; s <<= 1) {
            H2U me, ot;
            me.h = r;
            ot.u = (unsigned int)__shfl_xor((int)me.u, s, 64);
            r = ismax ? __builtin_elementwise_max(r, ot.h) : (r + ot.h);
        }
        if (q == 0) {
            if (ismax) {
                int b = 2 * dv;
                out[(size_t)b       * (2 * NK) + 2 * k] = (float)r.x;
                out[(size_t)(b + 1) * (2 * NK) + 2 * k] = (float)r.y;
            } else {
                int b = 2 * (dv - 4);
                float inv = 1.0f / (float)lk;
                out[(size_t)b       * (2 * NK) + 2 * k + 1] = (float)r.x * inv;
                out[(size_t)(b + 1) * (2 * NK) + 2 * k + 1] = (float)r.y * inv;
            }
        }
    }
}

extern "C" void kernel_launch(void* const* d_in, const int* in_sizes, int n_in,
                              void* d_out, int out_size, void* d_ws, size_t ws_size,
                              hipStream_t stream) {
    const float* x    = (const float*)d_in[0];
    const float* W    = (const float*)d_in[1];
    const float* bias = (const float*)d_in[2];
    const int*   dil  = (const int*)d_in[4];
    const int*   lo   = (const int*)d_in[5];
    float* out = (float*)d_out;

    rocket_kernel<<<NK / 4, 256, 0, stream>>>(x, W, bias, dil, lo, out);
}